// Round 1
// baseline (520.615 us; speedup 1.0000x reference)
//
#include <hip/hip_runtime.h>

#define BB 4
#define NN 400
#define DD 100
#define SS 512

__device__ __forceinline__ float prelu_f(float v, float a) { return v >= 0.f ? v : a * v; }

// ---------------- K1: G1[s,d] = prelu(sum_n G[s,n]*Wgf[d,n] + bgf[d]) ----------------
__global__ void k_g1(const float* __restrict__ G, const float* __restrict__ Wgf,
                     const float* __restrict__ bgf, const float* __restrict__ agf,
                     float* __restrict__ G1) {
    int idx = blockIdx.x * blockDim.x + threadIdx.x;
    if (idx >= SS * DD) return;
    int d = idx % DD, s = idx / DD;
    const float* g = G + s * NN;
    const float* w = Wgf + d * NN;
    float acc = 0.f;
    for (int n = 0; n < NN; ++n) acc += g[n] * w[n];
    G1[idx] = prelu_f(acc + bgf[d], agf[0]);
}

// ---------------- K2: Ax[b,s,d] = sum_n A[s,n]*x[b,n,d] ----------------
__global__ void k_ax(const float* __restrict__ A, const float* __restrict__ x,
                     float* __restrict__ Ax) {
    int idx = blockIdx.x * blockDim.x + threadIdx.x;
    if (idx >= BB * SS * DD) return;
    int d = idx % DD;
    int s = (idx / DD) % SS;
    int b = idx / (DD * SS);
    const float* a = A + s * NN;
    const float* xp = x + b * NN * DD + d;
    float acc = 0.f;
    for (int n = 0; n < NN; ++n) acc += a[n] * xp[n * DD];
    Ax[idx] = acc;
}

// ---------------- K3: scores + row softmax + sq, fused. block = (b,s), 512 thr ----------------
__global__ void k_scores(const float* __restrict__ G1, const float* __restrict__ Ax,
                         float* __restrict__ P, float* __restrict__ sq) {
    int bs = blockIdx.x;
    int b = bs / SS, s = bs % SS;
    int t = threadIdx.x;  // 0..511 == column index
    __shared__ float g1s[DD];
    __shared__ float red[512];
    for (int d = t; d < DD; d += 512) g1s[d] = G1[s * DD + d];
    __syncthreads();
    const float* ax = Ax + (b * SS + t) * DD;
    float acc = 0.f;
    for (int d = 0; d < DD; ++d) acc += g1s[d] * ax[d];
    // max
    red[t] = acc; __syncthreads();
    for (int off = 256; off > 0; off >>= 1) { if (t < off) red[t] = fmaxf(red[t], red[t + off]); __syncthreads(); }
    float m = red[0]; __syncthreads();
    float e = expf(acc - m);
    red[t] = e; __syncthreads();
    for (int off = 256; off > 0; off >>= 1) { if (t < off) red[t] += red[t + off]; __syncthreads(); }
    float ssum = red[0]; __syncthreads();
    float p = e / ssum;
    P[(b * SS + s) * SS + t] = p;
    red[t] = p * p; __syncthreads();
    for (int off = 256; off > 0; off >>= 1) { if (t < off) red[t] += red[t + off]; __syncthreads(); }
    if (t == 0) sq[bs] = red[0];
}

// ---------------- K4: Bm[b,i,k] = (i==k) ? 1 : sqrt(max(sq_i+sq_k-2*P_i.P_k,0)) ----------------
__global__ void k_bm(const float* __restrict__ P, const float* __restrict__ sq,
                     float* __restrict__ Bm) {
    int b = blockIdx.z;
    int i0 = blockIdx.y * 16, k0 = blockIdx.x * 16;
    int ty = threadIdx.y, tx = threadIdx.x;
    __shared__ float As[16][17], Bs[16][17];
    const float* Pb = P + b * SS * SS;
    float acc = 0.f;
    for (int j0 = 0; j0 < SS; j0 += 16) {
        As[ty][tx] = Pb[(i0 + ty) * SS + j0 + tx];
        Bs[ty][tx] = Pb[(k0 + ty) * SS + j0 + tx];
        __syncthreads();
#pragma unroll
        for (int jj = 0; jj < 16; ++jj) acc += As[ty][jj] * Bs[tx][jj];
        __syncthreads();
    }
    int i = i0 + ty, k = k0 + tx;
    float d2 = sq[b * SS + i] + sq[b * SS + k] - 2.f * acc;
    float dist = sqrtf(fmaxf(d2, 0.f));
    Bm[(b * SS + i) * SS + k] = (i == k) ? 1.f : dist;
}

// ---------------- K5: dh[row] = rsqrt(rowsum(Bm)) ----------------
__global__ void k_dh(const float* __restrict__ Bm, float* __restrict__ dh) {
    int row = blockIdx.x;  // b*S+i
    int t = threadIdx.x;   // 512
    __shared__ float red[512];
    red[t] = Bm[row * SS + t]; __syncthreads();
    for (int off = 256; off > 0; off >>= 1) { if (t < off) red[t] += red[t + off]; __syncthreads(); }
    if (t == 0) dh[row] = rsqrtf(red[0]);
}

// ---------------- K6: PW[b,s,d] = sum_t P[b,s,t]*Wg[d,t] ----------------
__global__ void k_pw(const float* __restrict__ P, const float* __restrict__ Wg,
                     float* __restrict__ PW) {
    int idx = blockIdx.x * blockDim.x + threadIdx.x;
    if (idx >= BB * SS * DD) return;
    int d = idx % DD;
    int s = (idx / DD) % SS;
    int b = idx / (DD * SS);
    const float* p = P + (b * SS + s) * SS;
    const float* w = Wg + d * SS;
    float acc = 0.f;
    for (int t = 0; t < SS; ++t) acc += p[t] * w[t];
    PW[idx] = acc;
}

// ---------------- K7: T1[b,i,d] = sum_k Bm[b,i,k]*PW[b,k,d] ----------------
__global__ void k_t1(const float* __restrict__ Bm, const float* __restrict__ PW,
                     float* __restrict__ T1) {
    int idx = blockIdx.x * blockDim.x + threadIdx.x;
    if (idx >= BB * SS * DD) return;
    int d = idx % DD;
    int i = (idx / DD) % SS;
    int b = idx / (DD * SS);
    const float* bm = Bm + (b * SS + i) * SS;
    const float* pw = PW + b * SS * DD + d;
    float acc = 0.f;
    for (int k = 0; k < SS; ++k) acc += bm[k] * pw[k * DD];
    T1[idx] = acc;
}

// ---------------- K8: gx[b,i,d] = relu(dh_i * sum_k Bm[i,k]*dh_k*T1[k,d] + bg[d]) ----------------
__global__ void k_gx(const float* __restrict__ Bm, const float* __restrict__ dh,
                     const float* __restrict__ T1, const float* __restrict__ bg,
                     float* __restrict__ gx) {
    int idx = blockIdx.x * blockDim.x + threadIdx.x;
    if (idx >= BB * SS * DD) return;
    int d = idx % DD;
    int i = (idx / DD) % SS;
    int b = idx / (DD * SS);
    const float* bm = Bm + (b * SS + i) * SS;
    const float* dhb = dh + b * SS;
    const float* t1 = T1 + b * SS * DD + d;
    float acc = 0.f;
    for (int k = 0; k < SS; ++k) acc += bm[k] * dhb[k] * t1[k * DD];
    float v = dhb[i] * acc + bg[d];
    gx[idx] = v > 0.f ? v : 0.f;
}

// ---------------- K9a: h1[b,n,d] = sum_e x[b,n,e]*W4a[d,e] ----------------
__global__ void k_h1(const float* __restrict__ x, const float* __restrict__ W4a,
                     float* __restrict__ h1) {
    int idx = blockIdx.x * blockDim.x + threadIdx.x;
    if (idx >= BB * NN * DD) return;
    int d = idx % DD;
    int n = (idx / DD) % NN;
    int b = idx / (DD * NN);
    const float* xp = x + (b * NN + n) * DD;
    const float* w = W4a + d * 2 * DD;
    float acc = 0.f;
    for (int e = 0; e < DD; ++e) acc += xp[e] * w[e];
    h1[idx] = acc;
}

// ---------------- K9b: h2[b,s,d] = sum_e gx[b,s,e]*W4a[d,D+e] ----------------
__global__ void k_h2(const float* __restrict__ gx, const float* __restrict__ W4a,
                     float* __restrict__ h2) {
    int idx = blockIdx.x * blockDim.x + threadIdx.x;
    if (idx >= BB * SS * DD) return;
    int d = idx % DD;
    int s = (idx / DD) % SS;
    int b = idx / (DD * SS);
    const float* g = gx + (b * SS + s) * DD;
    const float* w = W4a + d * 2 * DD + DD;
    float acc = 0.f;
    for (int e = 0; e < DD; ++e) acc += g[e] * w[e];
    h2[idx] = acc;
}

// ---------------- K10: logits over n + softmax over n. block = (b,s), 256 thr ----------------
// div stored as (b, s, n) so softmax axis is contiguous.
__global__ void k_div(const float* __restrict__ h1, const float* __restrict__ h2,
                      const float* __restrict__ b4a, const float* __restrict__ a4ap,
                      const float* __restrict__ W4b, const float* __restrict__ b4bp,
                      const float* __restrict__ a4bp, float* __restrict__ divO) {
    int bs = blockIdx.x;
    int b = bs / SS, s = bs % SS;
    int t = threadIdx.x;  // 256
    __shared__ float sh2[DD], sb4a[DD], sw[DD];
    __shared__ float L[NN];
    __shared__ float red[256];
    float a4a = a4ap[0], a4b = a4bp[0], bb4 = b4bp[0];
    for (int d = t; d < DD; d += 256) {
        sh2[d] = h2[(b * SS + s) * DD + d];
        sb4a[d] = b4a[d];
        sw[d] = W4b[d];
    }
    __syncthreads();
    for (int n = t; n < NN; n += 256) {
        const float* h1p = h1 + (b * NN + n) * DD;
        float acc = 0.f;
        for (int d = 0; d < DD; ++d) {
            float v = h1p[d] + sh2[d] + sb4a[d];
            acc += prelu_f(v, a4a) * sw[d];
        }
        L[n] = prelu_f(acc + bb4, a4b);
    }
    __syncthreads();
    float m = -INFINITY;
    for (int n = t; n < NN; n += 256) m = fmaxf(m, L[n]);
    red[t] = m; __syncthreads();
    for (int off = 128; off > 0; off >>= 1) { if (t < off) red[t] = fmaxf(red[t], red[t + off]); __syncthreads(); }
    m = red[0]; __syncthreads();
    float ssum = 0.f;
    for (int n = t; n < NN; n += 256) { float e = expf(L[n] - m); L[n] = e; ssum += e; }
    red[t] = ssum; __syncthreads();
    for (int off = 128; off > 0; off >>= 1) { if (t < off) red[t] += red[t + off]; __syncthreads(); }
    float sum = red[0]; __syncthreads();
    float inv = 1.f / sum;
    for (int n = t; n < NN; n += 256) divO[(b * SS + s) * NN + n] = L[n] * inv;
}

// ---------------- K11: tmp[b,n,d] = sum_s div[b,s,n]*gx[b,s,d] ----------------
__global__ void k_tmp(const float* __restrict__ divO, const float* __restrict__ gx,
                      float* __restrict__ tmp) {
    int idx = blockIdx.x * blockDim.x + threadIdx.x;
    if (idx >= BB * NN * DD) return;
    int d = idx % DD;
    int n = (idx / DD) % NN;
    int b = idx / (DD * NN);
    const float* dv = divO + b * SS * NN + n;
    const float* g = gx + b * SS * DD + d;
    float acc = 0.f;
    for (int s = 0; s < SS; ++s) acc += dv[s * NN] * g[s * DD];
    tmp[idx] = acc;
}

// ---------------- K12: out = prelu(tmp @ W5^T + b5, a5) + x ----------------
__global__ void k_out(const float* __restrict__ tmp, const float* __restrict__ W5,
                      const float* __restrict__ b5, const float* __restrict__ a5p,
                      const float* __restrict__ x, float* __restrict__ out) {
    int idx = blockIdx.x * blockDim.x + threadIdx.x;
    if (idx >= BB * NN * DD) return;
    int d = idx % DD;
    int bn = idx / DD;
    const float* tp = tmp + bn * DD;
    const float* w = W5 + d * DD;
    float acc = 0.f;
    for (int e = 0; e < DD; ++e) acc += tp[e] * w[e];
    out[idx] = prelu_f(acc + b5[d], a5p[0]) + x[idx];
}

extern "C" void kernel_launch(void* const* d_in, const int* in_sizes, int n_in,
                              void* d_out, int out_size, void* d_ws, size_t ws_size,
                              hipStream_t stream) {
    const float* x   = (const float*)d_in[0];
    const float* G   = (const float*)d_in[1];
    const float* A   = (const float*)d_in[2];
    const float* Wgf = (const float*)d_in[3];
    const float* bgf = (const float*)d_in[4];
    const float* agf = (const float*)d_in[5];
    const float* Wg  = (const float*)d_in[6];
    const float* bg  = (const float*)d_in[7];
    const float* W4a = (const float*)d_in[8];
    const float* b4a = (const float*)d_in[9];
    const float* a4a = (const float*)d_in[10];
    const float* W4b = (const float*)d_in[11];
    const float* b4b = (const float*)d_in[12];
    const float* a4b = (const float*)d_in[13];
    const float* W5  = (const float*)d_in[14];
    const float* b5  = (const float*)d_in[15];
    const float* a5  = (const float*)d_in[16];
    float* out = (float*)d_out;

    float* ws = (float*)d_ws;
    float* G1  = ws;                 // 51200
    float* Ax  = G1  + 51200;        // 204800
    float* P   = Ax  + 204800;       // 1048576
    float* sq  = P   + 1048576;      // 2048
    float* Bm  = sq  + 2048;         // 1048576
    float* dh  = Bm  + 1048576;      // 2048
    float* PW  = dh  + 2048;         // 204800
    float* T1  = PW  + 204800;       // 204800
    float* gx  = T1  + 204800;       // 204800
    float* h1  = gx  + 204800;       // 160000
    float* h2  = h1  + 160000;       // 204800
    float* dv  = h2  + 204800;       // 819200
    float* tmp = dv  + 819200;       // 160000

    k_g1<<<(SS * DD + 255) / 256, 256, 0, stream>>>(G, Wgf, bgf, agf, G1);
    k_ax<<<(BB * SS * DD + 255) / 256, 256, 0, stream>>>(A, x, Ax);
    k_scores<<<BB * SS, 512, 0, stream>>>(G1, Ax, P, sq);
    k_bm<<<dim3(SS / 16, SS / 16, BB), dim3(16, 16), 0, stream>>>(P, sq, Bm);
    k_dh<<<BB * SS, 512, 0, stream>>>(Bm, dh);
    k_pw<<<(BB * SS * DD + 255) / 256, 256, 0, stream>>>(P, Wg, PW);
    k_t1<<<(BB * SS * DD + 255) / 256, 256, 0, stream>>>(Bm, PW, T1);
    k_gx<<<(BB * SS * DD + 255) / 256, 256, 0, stream>>>(Bm, dh, T1, bg, gx);
    k_h1<<<(BB * NN * DD + 255) / 256, 256, 0, stream>>>(x, W4a, h1);
    k_h2<<<(BB * SS * DD + 255) / 256, 256, 0, stream>>>(gx, W4a, h2);
    k_div<<<BB * SS, 256, 0, stream>>>(h1, h2, b4a, a4a, W4b, b4b, a4b, dv);
    k_tmp<<<(BB * NN * DD + 255) / 256, 256, 0, stream>>>(dv, gx, tmp);
    k_out<<<(BB * NN * DD + 255) / 256, 256, 0, stream>>>(tmp, W5, b5, a5, x, out);
}